// Round 7
// baseline (392.033 us; speedup 1.0000x reference)
//
#include <hip/hip_runtime.h>
#include <cstddef>

// CSWinBlock on MI355X — round 10: fix round-9's write amplification (16-col strips = half
// cache lines -> WRITE_SIZE 3x). k_projmlp: 512 threads / 8 waves in 2x4 (wm=row-half,
// wn=col-group): each wave owns 32 rows x 32 cols -> full 128B-line stores. Weight regions
// (32 rows) shared by wm-pairs; restage ordered by existing lgkm barriers; both pair waves
// issue identical stages (benign) so each wave's vmcnt tracks its own copy.
// 16 waves/CU (vs round-7's 8) for latency hiding. k_ln_qkv/k_attn = round-4 forms.
// ws layout (<= 97 MB used):
//   [0, 32MB)    q-plane  bf16 [NTOK][128]  — attention(+LePE) output written IN-PLACE here
//   [32, 64MB)   k-plane  bf16 [NTOK][128]
//   [64, 96MB)   v-plane  bf16 [NTOK][128]
//   [96MB, +384KB) bf16 weights: wqkv[49152] wproj[16384] w1[65536] w2[65536]

#define LDIM 16384
#define NTOK 131072
#define PLANE ((size_t)NTOK * 128)

typedef __attribute__((ext_vector_type(8))) short bf16x8;
typedef __attribute__((ext_vector_type(4))) float f32x4;

__device__ __forceinline__ unsigned short f2bf(float f) {
  union { float f; unsigned int i; } u; u.f = f;
  unsigned int r = u.i + 0x7fffu + ((u.i >> 16) & 1u);
  return (unsigned short)(r >> 16);
}
__device__ __forceinline__ float bflo(unsigned int u) {
  union { unsigned int i; float f; } x; x.i = u << 16; return x.f;
}
__device__ __forceinline__ float bfhi(unsigned int u) {
  union { unsigned int i; float f; } x; x.i = u & 0xffff0000u; return x.f;
}
__device__ __forceinline__ unsigned int pk(float a, float b) {
  return (unsigned)f2bf(a) | ((unsigned)f2bf(b) << 16);
}

// async 16B global->LDS (wave-uniform LDS base + lane*16)
__device__ __forceinline__ void async16(const unsigned short* g, unsigned short* l) {
  __builtin_amdgcn_global_load_lds(
      (const __attribute__((address_space(1))) unsigned int*)g,
      (__attribute__((address_space(3))) unsigned int*)l, 16, 0, 0);
}

__device__ __forceinline__ void wait_lgkm0() {
  asm volatile("s_waitcnt lgkmcnt(0)" ::: "memory");
  __builtin_amdgcn_sched_barrier(0);
}
__device__ __forceinline__ void wait_vm0() {
  asm volatile("s_waitcnt vmcnt(0)" ::: "memory");
  __builtin_amdgcn_sched_barrier(0);
}
// barrier that does NOT drain vmcnt: LDS producer/consumer only (keeps prefetch in flight)
__device__ __forceinline__ void barrier_lgkm() {
  asm volatile("s_waitcnt lgkmcnt(0)" ::: "memory");
  __builtin_amdgcn_s_barrier();
  __builtin_amdgcn_sched_barrier(0);
}

// swizzled tile: element (row, col) lives at row*128 + ((col/8)^(row&7))*8 + col%8
__device__ __forceinline__ bf16x8 fragS(const unsigned short* base, int row, int c) {
  return *(const bf16x8*)(base + row * 128 + ((c ^ (row & 7)) << 3));
}

// stage 128x128 bf16 tile global->LDS, swizzled (block-cooperative, 256 threads)
__device__ __forceinline__ void stageS128(const unsigned short* __restrict__ src, int rowStride,
                                          unsigned short* dst, int tid) {
  const int lane = tid & 63, wv = tid >> 6;
  #pragma unroll
  for (int i = 0; i < 8; i++) {
    const int base = i * 256 + wv * 64;     // wave-uniform chunk base
    const int f = base + lane;
    const int row = f >> 4, cs = f & 15, cg = cs ^ (row & 7);
    async16(src + (size_t)row * rowStride + (cg << 3), dst + (size_t)base * 8);
  }
}

// stage 64x128 bf16 tile global->LDS, swizzled (block-cooperative, 512 threads)
__device__ __forceinline__ void stageS64b(const unsigned short* __restrict__ src,
                                          unsigned short* dst, int tid) {
  const int lane = tid & 63, wv = tid >> 6;
  #pragma unroll
  for (int i = 0; i < 2; i++) {
    const int base = i * 512 + wv * 64;
    const int f = base + lane;
    const int row = f >> 4, cs = f & 15, cg = cs ^ (row & 7);
    async16(src + (size_t)row * 128 + (cg << 3), dst + (size_t)base * 8);
  }
}

// PER-WAVE stage: 32 rows (8 KB) of a weight matrix into a ws region, swizzled.
// With shared regions, both waves of a pair issue identical stages (benign identical-write
// race); overwrites are ordered by the surrounding lgkm barriers.
__device__ __forceinline__ void stageW32(const unsigned short* __restrict__ src, int rowStride,
                                         unsigned short* dstRegion, int lane) {
  #pragma unroll
  for (int i = 0; i < 8; i++) {
    const int rowLocal = i * 4 + (lane >> 4);
    const int cs = lane & 15, cg = cs ^ (rowLocal & 7);
    async16(src + (size_t)rowLocal * rowStride + (cg << 3), dstRegion + i * 512);
  }
}

// 128x128x128 MFMA tile, 4 waves in 2x2 (k_ln_qkv)
__device__ __forceinline__ void gemmS(const unsigned short* As, const unsigned short* Bs,
                                      f32x4 acc[4][4], int wm, int wn, int q, int r) {
  #pragma unroll
  for (int kc = 0; kc < 4; kc++) {
    bf16x8 a[4], b[4];
    #pragma unroll
    for (int mt = 0; mt < 4; mt++) a[mt] = fragS(As, wm * 64 + mt * 16 + r, kc * 4 + q);
    #pragma unroll
    for (int nt = 0; nt < 4; nt++) b[nt] = fragS(Bs, wn * 64 + nt * 16 + r, kc * 4 + q);
    #pragma unroll
    for (int mt = 0; mt < 4; mt++)
      #pragma unroll
      for (int nt = 0; nt < 4; nt++)
        acc[mt][nt] = __builtin_amdgcn_mfma_f32_16x16x32_bf16(a[mt], b[nt], acc[mt][nt], 0, 0, 0);
  }
}

// C frags -> swizzled LDS (reuses B tile) -> coalesced bf16 global store (k_ln_qkv)
__device__ __forceinline__ void storeC(f32x4 acc[4][4], unsigned short* Cs,
                                       unsigned short* __restrict__ dst, int dstStride, int tid) {
  const int wv = tid >> 6, lane = tid & 63, q = lane >> 4, r = lane & 15;
  const int wm = wv & 1, wn = wv >> 1;
  #pragma unroll
  for (int mt = 0; mt < 4; mt++)
    #pragma unroll
    for (int nt = 0; nt < 4; nt++) {
      const int col = wn * 64 + nt * 16 + r;
      #pragma unroll
      for (int rg = 0; rg < 4; rg++) {
        const int row = wm * 64 + mt * 16 + q * 4 + rg;
        Cs[row * 128 + ((((col >> 3) ^ (row & 7)) << 3) | (col & 7))] = f2bf(acc[mt][nt][rg]);
      }
    }
  __syncthreads();
  #pragma unroll
  for (int i = 0; i < 8; i++) {
    const int f = tid + i * 256;
    const int row = f >> 4, cs = f & 15, cg = cs ^ (row & 7);
    *(uint4*)(dst + (size_t)row * dstStride + (cg << 3)) = *(const uint4*)(Cs + row * 128 + cs * 8);
  }
}

// gelu tanh-approx: x*sigmoid(1.59576912*(x+0.044715x^3)) = x*rcp(1+exp2(-k*(...)))
__device__ __forceinline__ float gelu_t(float x) {
  const float y = -2.3022083f * (x + 0.044715f * x * x * x);  // -1.59576912*log2(e)*(...)
  const float p = __builtin_amdgcn_exp2f(y);
  return x * __builtin_amdgcn_rcpf(1.f + p);
}

// ================= Kernel 0: weights fp32 -> bf16 =================
__global__ void k_prep(const float* __restrict__ wq, const float* __restrict__ wp,
                       const float* __restrict__ w1, const float* __restrict__ w2,
                       unsigned short* __restrict__ wb)
{
  const int id = blockIdx.x * 256 + threadIdx.x;   // 49152 threads, 4 elems each
  const float* src; int off;
  if (id < 12288)      { src = wq; off = id; }
  else if (id < 16384) { src = wp; off = id - 12288; }
  else if (id < 32768) { src = w1; off = id - 16384; }
  else                 { src = w2; off = id - 32768; }
  const float4 v = *(const float4*)(src + (size_t)off * 4);
  uint2 u; u.x = pk(v.x, v.y); u.y = pk(v.z, v.w);
  *(uint2*)(wb + (size_t)id * 4) = u;
}

// ================= Kernel 1: LN1 + QKV GEMM (round-4 staged form) =================
__global__ __launch_bounds__(256, 2) void k_ln_qkv(
    const float* __restrict__ x, const float* __restrict__ g, const float* __restrict__ bb,
    const unsigned short* __restrict__ wqkvb, unsigned short* __restrict__ qkv)
{
  __shared__ unsigned short xs[128 * 128];
  __shared__ unsigned short ws[128 * 128];
  __shared__ float redS[128][2], redQ[128][2];
  const int tid = threadIdx.x;
  const long m0 = (long)blockIdx.x * 128;
  { // LN: 2 threads/row
    const int m = tid >> 1, hf = tid & 1;
    const float4* xg = (const float4*)(x + (size_t)(m0 + m) * 128 + hf * 64);
    float4 xv[16];
    #pragma unroll
    for (int i = 0; i < 16; i++) xv[i] = xg[i];
    float s1 = 0.f, s2 = 0.f;
    #pragma unroll
    for (int i = 0; i < 16; i++) {
      s1 += xv[i].x + xv[i].y + xv[i].z + xv[i].w;
      s2 += xv[i].x * xv[i].x + xv[i].y * xv[i].y + xv[i].z * xv[i].z + xv[i].w * xv[i].w;
    }
    redS[m][hf] = s1; redQ[m][hf] = s2;
    __syncthreads();
    const float mean = (redS[m][0] + redS[m][1]) * (1.f / 128.f);
    const float var  = (redQ[m][0] + redQ[m][1]) * (1.f / 128.f) - mean * mean;
    const float rs = rsqrtf(var + 1e-5f);
    const float4* g4 = (const float4*)(g + hf * 64);
    const float4* b4 = (const float4*)(bb + hf * 64);
    #pragma unroll
    for (int i = 0; i < 8; i++) {
      float4 v0 = xv[2 * i], v1 = xv[2 * i + 1];
      float4 g0 = g4[2 * i], g1 = g4[2 * i + 1], p0 = b4[2 * i], p1 = b4[2 * i + 1];
      uint4 u;
      u.x = pk((v0.x - mean) * rs * g0.x + p0.x, (v0.y - mean) * rs * g0.y + p0.y);
      u.y = pk((v0.z - mean) * rs * g0.z + p0.z, (v0.w - mean) * rs * g0.w + p0.w);
      u.z = pk((v1.x - mean) * rs * g1.x + p1.x, (v1.y - mean) * rs * g1.y + p1.y);
      u.w = pk((v1.z - mean) * rs * g1.z + p1.z, (v1.w - mean) * rs * g1.w + p1.w);
      const int c = hf * 8 + i;
      *(uint4*)&xs[m * 128 + ((c ^ (m & 7)) << 3)] = u;
    }
  }
  const int lane = tid & 63, q = lane >> 4, r = lane & 15;
  const int wv = tid >> 6, wm = wv & 1, wn = wv >> 1;
  for (int nc = 0; nc < 3; nc++) {
    __syncthreads();                             // xs ready / prior readout done
    stageS128(wqkvb + (size_t)nc * 16384, 128, ws, tid);
    __syncthreads();                             // ws ready
    f32x4 acc[4][4];
    #pragma unroll
    for (int a = 0; a < 4; a++)
      #pragma unroll
      for (int b = 0; b < 4; b++) acc[a][b] = f32x4{0.f, 0.f, 0.f, 0.f};
    gemmS(xs, ws, acc, wm, wn, q, r);
    __syncthreads();                             // ws reads done (reused as Cs)
    storeC(acc, ws, qkv + (size_t)nc * PLANE + (size_t)m0 * 128, 128, tid);
  }
}

// ================= Kernel 2: CSWin attention + fused LePE (in-place into q-plane) ==========
__global__ __launch_bounds__(256, 2) void k_attn(
    const unsigned short* __restrict__ qkv,
    const float* __restrict__ conv_w0, const float* __restrict__ conv_b0,
    const float* __restrict__ conv_w1, const float* __restrict__ conv_b1,
    unsigned short* __restrict__ att)
{
  __shared__ unsigned short Kt[256][40];
  __shared__ unsigned short Vt[32][264];
  __shared__ unsigned short Ps[4][64][72];
  const unsigned short* kpl = qkv + PLANE;
  const unsigned short* vpl = qkv + 2 * PLANE;
  const int t = threadIdx.x;
  const int win = blockIdx.x, head = blockIdx.y, br = blockIdx.z;
  const int bimg = win >> 6, widx = win & 63;
  const int c0 = br * 64 + head * 32;
  const int lgWs = (br == 0) ? 1 : 7;
  const int Wsm1 = (1 << lgWs) - 1;
  const long base = (long)bimg * LDIM + ((br == 0) ? widx * 2 : widx * 256);

  { // stage K + V^T (thread t = key t)
    const long tj = base + (long)(t >> lgWs) * 128 + (t & Wsm1);
    const uint4* kp = (const uint4*)(kpl + (size_t)tj * 128 + c0);
    uint4 k0v = kp[0], k1v = kp[1], k2v = kp[2], k3v = kp[3];
    *(uint4*)&Kt[t][0]  = k0v;  *(uint4*)&Kt[t][8]  = k1v;
    *(uint4*)&Kt[t][16] = k2v;  *(uint4*)&Kt[t][24] = k3v;
    const uint4* vp = (const uint4*)(vpl + (size_t)tj * 128 + c0);
    uint4 vv[4] = {vp[0], vp[1], vp[2], vp[3]};
    const unsigned short* vs = (const unsigned short*)vv;
    #pragma unroll
    for (int d = 0; d < 32; d++) Vt[d][t] = vs[d];
  }
  const int wave = t >> 6, lane = t & 63, q = lane >> 4, r = lane & 15;
  const int qbase = wave * 64;
  bf16x8 qf[4];
  #pragma unroll
  for (int mt = 0; mt < 4; mt++) {
    const int row = qbase + mt * 16 + r;
    const long tok = base + (long)(row >> lgWs) * 128 + (row & Wsm1);
    qf[mt] = *(const bf16x8*)(qkv + (size_t)tok * 128 + c0 + q * 8);
  }
  __syncthreads();

  const float factor = 0.17677669529663687f * 1.44269504088896341f;
  f32x4 Oacc[4][2];
  float psum[4][4];
  #pragma unroll
  for (int mt = 0; mt < 4; mt++) {
    Oacc[mt][0] = f32x4{0.f, 0.f, 0.f, 0.f};
    Oacc[mt][1] = f32x4{0.f, 0.f, 0.f, 0.f};
    #pragma unroll
    for (int rg = 0; rg < 4; rg++) psum[mt][rg] = 0.f;
  }

  for (int kc = 0; kc < 4; kc++) {
    bf16x8 kb[4];
    #pragma unroll
    for (int nt = 0; nt < 4; nt++) kb[nt] = *(const bf16x8*)&Kt[kc * 64 + nt * 16 + r][q * 8];
    f32x4 s[4][4];
    #pragma unroll
    for (int mt = 0; mt < 4; mt++)
      #pragma unroll
      for (int nt = 0; nt < 4; nt++) {
        f32x4 z = f32x4{0.f, 0.f, 0.f, 0.f};
        s[mt][nt] = __builtin_amdgcn_mfma_f32_16x16x32_bf16(qf[mt], kb[nt], z, 0, 0, 0);
      }
    #pragma unroll
    for (int mt = 0; mt < 4; mt++)
      #pragma unroll
      for (int nt = 0; nt < 4; nt++)
        #pragma unroll
        for (int rg = 0; rg < 4; rg++) {
          const float p = __builtin_amdgcn_exp2f(s[mt][nt][rg] * factor);   // max-free
          psum[mt][rg] += p;
          Ps[wave][mt * 16 + q * 4 + rg][nt * 16 + r] = f2bf(p);
        }
    #pragma unroll
    for (int kst = 0; kst < 2; kst++) {
      bf16x8 pa[4], vb[2];
      #pragma unroll
      for (int mt = 0; mt < 4; mt++) pa[mt] = *(const bf16x8*)&Ps[wave][mt * 16 + r][kst * 32 + q * 8];
      #pragma unroll
      for (int nto = 0; nto < 2; nto++) vb[nto] = *(const bf16x8*)&Vt[nto * 16 + r][kc * 64 + kst * 32 + q * 8];
      #pragma unroll
      for (int mt = 0; mt < 4; mt++)
        #pragma unroll
        for (int nto = 0; nto < 2; nto++)
          Oacc[mt][nto] = __builtin_amdgcn_mfma_f32_16x16x32_bf16(pa[mt], vb[nto], Oacc[mt][nto], 0, 0, 0);
    }
  }

  #pragma unroll
  for (int mt = 0; mt < 4; mt++)
    #pragma unroll
    for (int rg = 0; rg < 4; rg++) {
      float v = psum[mt][rg];
      v += __shfl_xor(v, 1); v += __shfl_xor(v, 2);
      v += __shfl_xor(v, 4); v += __shfl_xor(v, 8);
      psum[mt][rg] = __builtin_amdgcn_rcpf(v);
    }

  // ---- fused LePE: depthwise 3x3 over the window, V already staged in Vt ----
  const float* cw = br ? conv_w1 : conv_w0;
  const float* cb = br ? conv_b1 : conv_b0;
  float wle[2][9], ble[2];
  #pragma unroll
  for (int nto = 0; nto < 2; nto++) {
    const int ch = head * 32 + nto * 16 + r;      // channel within branch (0..63)
    ble[nto] = cb[ch];
    #pragma unroll
    for (int tp = 0; tp < 9; tp++) wle[nto][tp] = cw[ch * 9 + tp];
  }
  const int WsW = 1 << lgWs;          // 2 (br0) or 128 (br1)
  const int HsW = 256 >> lgWs;        // 128 (br0) or 2 (br1)

  #pragma unroll
  for (int mt = 0; mt < 4; mt++)
    #pragma unroll
    for (int rg = 0; rg < 4; rg++) {
      const int row = qbase + mt * 16 + q * 4 + rg;      // window token 0..255
      const int ii = row >> lgWs, jj = row & Wsm1;
      const long tok = base + (long)ii * 128 + jj;
      float lep0 = ble[0], lep1 = ble[1];
      #pragma unroll
      for (int di = -1; di <= 1; di++) {
        if ((unsigned)(ii + di) >= (unsigned)HsW) continue;
        #pragma unroll
        for (int dj = -1; dj <= 1; dj++) {
          if ((unsigned)(jj + dj) >= (unsigned)WsW) continue;
          const int nb = row + di * WsW + dj;            // neighbor window token
          const int tap = (di + 1) * 3 + (dj + 1);
          lep0 = fmaf(bflo(Vt[r][nb]),      wle[0][tap], lep0);
          lep1 = fmaf(bflo(Vt[16 + r][nb]), wle[1][tap], lep1);
        }
      }
      const float pr = psum[mt][rg];
      att[(size_t)tok * 128 + c0 + r]      = f2bf(Oacc[mt][0][rg] * pr + lep0);
      att[(size_t)tok * 128 + c0 + 16 + r] = f2bf(Oacc[mt][1][rg] * pr + lep1);
    }
}

// ========== Kernel 3: fused proj + residual + LN2 + FFN1 + GELU + FFN2 + residual ==========
// 512 threads / 8 waves in 2x4: wave (wm=wv>>2, wn=wv&3) owns rows [wm*32,+32) x cols
// [wn*32,+32). Full 128B-line out stores. ws = 4 regions of 32 rows, shared by wm-pairs;
// restage ordered by lgkm barriers (both pair waves issue identical stages).
__global__ __launch_bounds__(512, 4) void k_projmlp(
    const unsigned short* __restrict__ att, const unsigned short* __restrict__ wprojb,
    const float* __restrict__ b_proj, const float* __restrict__ x,
    const float* __restrict__ g, const float* __restrict__ bb,
    const unsigned short* __restrict__ w1b, const unsigned short* __restrict__ w2b,
    const float* __restrict__ b1, const float* __restrict__ b2,
    float* __restrict__ out)
{
  __shared__ unsigned short hs[64 * 128];   // att tile (proj A), later gelu(h)
  __shared__ unsigned short xs[64 * 128];   // LN2 output (bf16, swizzled)
  __shared__ unsigned short ws[128 * 128];  // 4 regions x 32 rows x 128 (8 KB each)
  __shared__ float redS[64][4], redQ[64][4];
  const int tid = threadIdx.x;
  const long m0 = (long)blockIdx.x * 64;
  const int lane = tid & 63, q = lane >> 4, r = lane & 15, wv = tid >> 6;
  const int wm = wv >> 2, wn = wv & 3;
  unsigned short* wsR = ws + (size_t)wn * 32 * 128;   // region shared by the wm-pair

  stageS64b(att + (size_t)m0 * 128, hs, tid);
  stageW32(wprojb + (size_t)(wn * 32) * 128, 128, wsR, lane);   // both pair waves: identical

  // hoisted residual/param loads — independent of the staging above
  float xv[2][2][4];
  #pragma unroll
  for (int mt = 0; mt < 2; mt++)
    #pragma unroll
    for (int nt = 0; nt < 2; nt++) {
      const int col = wn * 32 + nt * 16 + r;
      #pragma unroll
      for (int rg = 0; rg < 4; rg++)
        xv[mt][nt][rg] = x[(size_t)(m0 + wm * 32 + mt * 16 + q * 4 + rg) * 128 + col];
    }
  float bpv[2], gv[2], bv2[2], b1v[4][2], b2v[2];
  #pragma unroll
  for (int nt = 0; nt < 2; nt++) {
    const int col = wn * 32 + nt * 16 + r;
    bpv[nt] = b_proj[col]; gv[nt] = g[col]; bv2[nt] = bb[col]; b2v[nt] = b2[col];
    #pragma unroll
    for (int nc = 0; nc < 4; nc++) b1v[nc][nt] = b1[nc * 128 + col];
  }
  __syncthreads();                                 // full drain: hs + wproj landed, all waves

  // ---- proj GEMM: rows wm*32+mt*16+q*4+rg, cols wn*32+nt*16+r
  f32x4 xres[2][2];
  #pragma unroll
  for (int mt = 0; mt < 2; mt++) { xres[mt][0] = f32x4{0.f,0.f,0.f,0.f}; xres[mt][1] = f32x4{0.f,0.f,0.f,0.f}; }
  #pragma unroll
  for (int kc = 0; kc < 4; kc++) {
    bf16x8 a[2], b[2];
    #pragma unroll
    for (int mt = 0; mt < 2; mt++) a[mt] = fragS(hs, wm * 32 + mt * 16 + r, kc * 4 + q);
    #pragma unroll
    for (int nt = 0; nt < 2; nt++) b[nt] = fragS(wsR, nt * 16 + r, kc * 4 + q);
    #pragma unroll
    for (int mt = 0; mt < 2; mt++)
      #pragma unroll
      for (int nt = 0; nt < 2; nt++)
        xres[mt][nt] = __builtin_amdgcn_mfma_f32_16x16x32_bf16(a[mt], b[nt], xres[mt][nt], 0, 0, 0);
  }
  // residual add
  #pragma unroll
  for (int mt = 0; mt < 2; mt++)
    #pragma unroll
    for (int nt = 0; nt < 2; nt++)
      #pragma unroll
      for (int rg = 0; rg < 4; rg++)
        xres[mt][nt][rg] += xv[mt][nt][rg] + bpv[nt];

  // ---- LN2 stats: wave covers 32 cols -> shfl over r; cross-group (4 wn) via LDS
  #pragma unroll
  for (int mt = 0; mt < 2; mt++)
    #pragma unroll
    for (int rg = 0; rg < 4; rg++) {
      float s1 = xres[mt][0][rg] + xres[mt][1][rg];
      float s2 = xres[mt][0][rg] * xres[mt][0][rg] + xres[mt][1][rg] * xres[mt][1][rg];
      s1 += __shfl_xor(s1, 1); s1 += __shfl_xor(s1, 2); s1 += __shfl_xor(s1, 4); s1 += __shfl_xor(s1, 8);
      s2 += __shfl_xor(s2, 1); s2 += __shfl_xor(s2, 2); s2 += __shfl_xor(s2, 4); s2 += __shfl_xor(s2, 8);
      if (r == 0) { const int row = wm * 32 + mt * 16 + q * 4 + rg; redS[row][wn] = s1; redQ[row][wn] = s2; }
    }
  barrier_lgkm();                                  // red ready; ALL waves' wproj reads drained
  stageW32(w1b + (size_t)(wn * 32) * 128, 128, wsR, lane);   // w1[0] (covered by normalize)
  #pragma unroll
  for (int mt = 0; mt < 2; mt++)
    #pragma unroll
    for (int rg = 0; rg < 4; rg++) {
      const int row = wm * 32 + mt * 16 + q * 4 + rg;
      const float s1 = redS[row][0] + redS[row][1] + redS[row][2] + redS[row][3];
      const float s2 = redQ[row][0] + redQ[row][1] + redQ[row][2] + redQ[row][3];
      const float mean = s1 * (1.f / 128.f);
      const float var  = s2 * (1.f / 128.f) - mean * mean;
      const float rs = rsqrtf(var + 1e-5f);
      #pragma unroll
      for (int nt = 0; nt < 2; nt++) {
        const int col = wn * 32 + nt * 16 + r;
        const float v = (xres[mt][nt][rg] - mean) * rs * gv[nt] + bv2[nt];
        xs[row * 128 + ((((col >> 3) ^ (row & 7)) << 3) | (col & 7))] = f2bf(v);
      }
    }
  barrier_lgkm();                                  // xs ready

  // ---- MLP: 4 Dff chunks of 128; pipelined shared-region weight staging
  f32x4 oacc[2][2];
  #pragma unroll
  for (int mt = 0; mt < 2; mt++) { oacc[mt][0] = f32x4{0.f,0.f,0.f,0.f}; oacc[mt][1] = f32x4{0.f,0.f,0.f,0.f}; }

  for (int nc = 0; nc < 4; nc++) {
    wait_vm0();                                    // own w1[nc] stage landed
    bf16x8 b1f[4][2];
    #pragma unroll
    for (int kc = 0; kc < 4; kc++)
      #pragma unroll
      for (int nt = 0; nt < 2; nt++)
        b1f[kc][nt] = fragS(wsR, nt * 16 + r, kc * 4 + q);
    // GEMM1: A from xs (own row half), B from registers
    f32x4 h[2][2];
    #pragma unroll
    for (int mt = 0; mt < 2; mt++) { h[mt][0] = f32x4{0.f,0.f,0.f,0.f}; h[mt][1] = f32x4{0.f,0.f,0.f,0.f}; }
    #pragma unroll
    for (int kc = 0; kc < 4; kc++) {
      bf16x8 a[2];
      #pragma unroll
      for (int mt = 0; mt < 2; mt++) a[mt] = fragS(xs, wm * 32 + mt * 16 + r, kc * 4 + q);
      #pragma unroll
      for (int mt = 0; mt < 2; mt++)
        #pragma unroll
        for (int nt = 0; nt < 2; nt++)
          h[mt][nt] = __builtin_amdgcn_mfma_f32_16x16x32_bf16(a[mt], b1f[kc][nt], h[mt][nt], 0, 0, 0);
    }
    barrier_lgkm();              // all b1f reads + prev-iter hs reads drained -> safe to restage/overwrite
    stageW32(w2b + (size_t)(wn * 32) * 512 + nc * 128, 512, wsR, lane);   // w2[nc] in flight
    // gelu -> hs (own 32x32 block)
    #pragma unroll
    for (int mt = 0; mt < 2; mt++)
      #pragma unroll
      for (int nt = 0; nt < 2; nt++) {
        const int col = wn * 32 + nt * 16 + r;
        const float bv = b1v[nc][nt];
        #pragma unroll
        for (int rg = 0; rg < 4; rg++) {
          const int rw = wm * 32 + mt * 16 + q * 4 + rg;
          hs[rw * 128 + ((((col >> 3) ^ (rw & 7)) << 3) | (col & 7))] = f2bf(gelu_t(h[mt][nt][rg] + bv));
        }
      }
    barrier_lgkm();                                // hs = gelu(h) ready
    wait_vm0();                                    // own w2[nc] stage landed
    bf16x8 b2f[4][2];
    #pragma unroll
    for (int kc = 0; kc < 4; kc++)
      #pragma unroll
      for (int nt = 0; nt < 2; nt++)
        b2f[kc][nt] = fragS(wsR, nt * 16 + r, kc * 4 + q);
    barrier_lgkm();                                // all b2f reads drained -> safe to restage
    if (nc < 3)
      stageW32(w1b + (size_t)((nc + 1) * 128 + wn * 32) * 128, 128, wsR, lane);  // w1[nc+1] in flight
    // GEMM2: A from hs (own row half, all cols), B from registers
    #pragma unroll
    for (int kc = 0; kc < 4; kc++) {
      bf16x8 a[2];
      #pragma unroll
      for (int mt = 0; mt < 2; mt++) a[mt] = fragS(hs, wm * 32 + mt * 16 + r, kc * 4 + q);
      #pragma unroll
      for (int mt = 0; mt < 2; mt++)
        #pragma unroll
        for (int nt = 0; nt < 2; nt++)
          oacc[mt][nt] = __builtin_amdgcn_mfma_f32_16x16x32_bf16(a[mt], b2f[kc][nt], oacc[mt][nt], 0, 0, 0);
    }
  }
  // ---- epilogue: out = xres + b2 + mlp  (single write, full 128B lines per wave)
  #pragma unroll
  for (int mt = 0; mt < 2; mt++)
    #pragma unroll
    for (int nt = 0; nt < 2; nt++) {
      const float bv = b2v[nt];
      const int col = wn * 32 + nt * 16 + r;
      #pragma unroll
      for (int rg = 0; rg < 4; rg++) {
        const size_t idx = (size_t)(m0 + wm * 32 + mt * 16 + q * 4 + rg) * 128 + col;
        out[idx] = xres[mt][nt][rg] + bv + oacc[mt][nt][rg];
      }
    }
}

extern "C" void kernel_launch(void* const* d_in, const int* in_sizes, int n_in,
                              void* d_out, int out_size, void* d_ws, size_t ws_size,
                              hipStream_t stream) {
  const float* x       = (const float*)d_in[0];
  const float* ln1_g   = (const float*)d_in[1];
  const float* ln1_b   = (const float*)d_in[2];
  const float* w_qkv   = (const float*)d_in[3];
  const float* w_proj  = (const float*)d_in[4];
  const float* b_proj  = (const float*)d_in[5];
  const float* conv_w0 = (const float*)d_in[6];
  const float* conv_b0 = (const float*)d_in[7];
  const float* conv_w1 = (const float*)d_in[8];
  const float* conv_b1 = (const float*)d_in[9];
  const float* ln2_g   = (const float*)d_in[10];
  const float* ln2_b   = (const float*)d_in[11];
  const float* w1      = (const float*)d_in[12];
  const float* b1      = (const float*)d_in[13];
  const float* w2      = (const float*)d_in[14];
  const float* b2      = (const float*)d_in[15];
  float* out = (float*)d_out;

  unsigned short* qkv = (unsigned short*)d_ws;     // 3 planes [NTOK][128]
  unsigned short* att = qkv;                       // attention(+LePE) output in-place in q-plane
  unsigned short* wb  = qkv + 3 * PLANE;           // bf16 weights
  unsigned short* wqkvb  = wb;
  unsigned short* wprojb = wb + 49152;
  unsigned short* w1b    = wb + 65536;
  unsigned short* w2b    = wb + 131072;

  k_prep<<<dim3(192), 256, 0, stream>>>(w_qkv, w_proj, w1, w2, wb);
  k_ln_qkv<<<dim3(NTOK / 128), 256, 0, stream>>>(x, ln1_g, ln1_b, wqkvb, qkv);
  k_attn<<<dim3(512, 2, 2), 256, 0, stream>>>(qkv, conv_w0, conv_b0, conv_w1, conv_b1, att);
  k_projmlp<<<dim3(NTOK / 64), 512, 0, stream>>>(att, wprojb, b_proj, x, ln2_g, ln2_b,
                                                 w1b, w2b, b1, b2, out);
}

// Round 8
// 348.023 us; speedup vs baseline: 1.1265x; 1.1265x over previous
//
#include <hip/hip_runtime.h>
#include <cstddef>

// CSWinBlock on MI355X — round 11: revert to the proven 345-us structure (256-thread
// k_projmlp, 2 blocks/CU, 32-col wave strips -> WRITE_SIZE=65MB exact). Two deltas:
// (1) k_projmlp weights now global->REGISTER with one-phase-ahead prefetch (T14): removes
//     all weight vmcnt stalls + the ws LDS round-trip; xs padded +32KB so LDS stays 66KB
//     -> still 2 blocks/CU (round-5 lesson: 3 blocks/CU thrashes L2).
// (2) k_ln_qkv: wqkv[0] stage hoisted before the LN phase (saves one full-drain stall).
// k_attn = exact round-7 form.
// ws layout (<= 97 MB used):
//   [0, 32MB)    q-plane  bf16 [NTOK][128]  — attention(+LePE) output written IN-PLACE here
//   [32, 64MB)   k-plane  bf16 [NTOK][128]
//   [64, 96MB)   v-plane  bf16 [NTOK][128]
//   [96MB, +384KB) bf16 weights: wqkv[49152] wproj[16384] w1[65536] w2[65536]

#define LDIM 16384
#define NTOK 131072
#define PLANE ((size_t)NTOK * 128)

typedef __attribute__((ext_vector_type(8))) short bf16x8;
typedef __attribute__((ext_vector_type(4))) float f32x4;

__device__ __forceinline__ unsigned short f2bf(float f) {
  union { float f; unsigned int i; } u; u.f = f;
  unsigned int r = u.i + 0x7fffu + ((u.i >> 16) & 1u);
  return (unsigned short)(r >> 16);
}
__device__ __forceinline__ float bflo(unsigned int u) {
  union { unsigned int i; float f; } x; x.i = u << 16; return x.f;
}
__device__ __forceinline__ unsigned int pk(float a, float b) {
  return (unsigned)f2bf(a) | ((unsigned)f2bf(b) << 16);
}

// async 16B global->LDS (wave-uniform LDS base + lane*16)
__device__ __forceinline__ void async16(const unsigned short* g, unsigned short* l) {
  __builtin_amdgcn_global_load_lds(
      (const __attribute__((address_space(1))) unsigned int*)g,
      (__attribute__((address_space(3))) unsigned int*)l, 16, 0, 0);
}

// barrier that does NOT drain vmcnt: LDS producer/consumer only
__device__ __forceinline__ void barrier_lgkm() {
  asm volatile("s_waitcnt lgkmcnt(0)" ::: "memory");
  __builtin_amdgcn_s_barrier();
  __builtin_amdgcn_sched_barrier(0);
}

// swizzled tile: element (row, col) lives at row*128 + ((col/8)^(row&7))*8 + col%8
__device__ __forceinline__ bf16x8 fragS(const unsigned short* base, int row, int c) {
  return *(const bf16x8*)(base + row * 128 + ((c ^ (row & 7)) << 3));
}

// direct global bf16x8 (one global_load_dwordx4)
__device__ __forceinline__ bf16x8 ldw(const unsigned short* p) {
  return *(const bf16x8*)p;
}

// stage 128x128 bf16 tile global->LDS, swizzled (block-cooperative, 256 threads)
__device__ __forceinline__ void stageS128(const unsigned short* __restrict__ src, int rowStride,
                                          unsigned short* dst, int tid) {
  const int lane = tid & 63, wv = tid >> 6;
  #pragma unroll
  for (int i = 0; i < 8; i++) {
    const int base = i * 256 + wv * 64;     // wave-uniform chunk base
    const int f = base + lane;
    const int row = f >> 4, cs = f & 15, cg = cs ^ (row & 7);
    async16(src + (size_t)row * rowStride + (cg << 3), dst + (size_t)base * 8);
  }
}

// stage 64x128 bf16 tile global->LDS, swizzled (block-cooperative, 256 threads)
__device__ __forceinline__ void stageS64(const unsigned short* __restrict__ src,
                                         unsigned short* dst, int tid) {
  const int lane = tid & 63, wv = tid >> 6;
  #pragma unroll
  for (int i = 0; i < 4; i++) {
    const int base = i * 256 + wv * 64;
    const int f = base + lane;
    const int row = f >> 4, cs = f & 15, cg = cs ^ (row & 7);
    async16(src + (size_t)row * 128 + (cg << 3), dst + (size_t)base * 8);
  }
}

// 128x128x128 MFMA tile, 4 waves in 2x2 (k_ln_qkv)
__device__ __forceinline__ void gemmS(const unsigned short* As, const unsigned short* Bs,
                                      f32x4 acc[4][4], int wm, int wn, int q, int r) {
  #pragma unroll
  for (int kc = 0; kc < 4; kc++) {
    bf16x8 a[4], b[4];
    #pragma unroll
    for (int mt = 0; mt < 4; mt++) a[mt] = fragS(As, wm * 64 + mt * 16 + r, kc * 4 + q);
    #pragma unroll
    for (int nt = 0; nt < 4; nt++) b[nt] = fragS(Bs, wn * 64 + nt * 16 + r, kc * 4 + q);
    #pragma unroll
    for (int mt = 0; mt < 4; mt++)
      #pragma unroll
      for (int nt = 0; nt < 4; nt++)
        acc[mt][nt] = __builtin_amdgcn_mfma_f32_16x16x32_bf16(a[mt], b[nt], acc[mt][nt], 0, 0, 0);
  }
}

// C frags -> swizzled LDS (reuses B tile) -> coalesced bf16 global store (k_ln_qkv)
__device__ __forceinline__ void storeC(f32x4 acc[4][4], unsigned short* Cs,
                                       unsigned short* __restrict__ dst, int dstStride, int tid) {
  const int wv = tid >> 6, lane = tid & 63, q = lane >> 4, r = lane & 15;
  const int wm = wv & 1, wn = wv >> 1;
  #pragma unroll
  for (int mt = 0; mt < 4; mt++)
    #pragma unroll
    for (int nt = 0; nt < 4; nt++) {
      const int col = wn * 64 + nt * 16 + r;
      #pragma unroll
      for (int rg = 0; rg < 4; rg++) {
        const int row = wm * 64 + mt * 16 + q * 4 + rg;
        Cs[row * 128 + ((((col >> 3) ^ (row & 7)) << 3) | (col & 7))] = f2bf(acc[mt][nt][rg]);
      }
    }
  __syncthreads();
  #pragma unroll
  for (int i = 0; i < 8; i++) {
    const int f = tid + i * 256;
    const int row = f >> 4, cs = f & 15, cg = cs ^ (row & 7);
    *(uint4*)(dst + (size_t)row * dstStride + (cg << 3)) = *(const uint4*)(Cs + row * 128 + cs * 8);
  }
}

// gelu tanh-approx: x*sigmoid(1.59576912*(x+0.044715x^3)) = x*rcp(1+exp2(-k*(...)))
__device__ __forceinline__ float gelu_t(float x) {
  const float y = -2.3022083f * (x + 0.044715f * x * x * x);  // -1.59576912*log2(e)*(...)
  const float p = __builtin_amdgcn_exp2f(y);
  return x * __builtin_amdgcn_rcpf(1.f + p);
}

// ================= Kernel 0: weights fp32 -> bf16 =================
__global__ void k_prep(const float* __restrict__ wq, const float* __restrict__ wp,
                       const float* __restrict__ w1, const float* __restrict__ w2,
                       unsigned short* __restrict__ wb)
{
  const int id = blockIdx.x * 256 + threadIdx.x;   // 49152 threads, 4 elems each
  const float* src; int off;
  if (id < 12288)      { src = wq; off = id; }
  else if (id < 16384) { src = wp; off = id - 12288; }
  else if (id < 32768) { src = w1; off = id - 16384; }
  else                 { src = w2; off = id - 32768; }
  const float4 v = *(const float4*)(src + (size_t)off * 4);
  uint2 u; u.x = pk(v.x, v.y); u.y = pk(v.z, v.w);
  *(uint2*)(wb + (size_t)id * 4) = u;
}

// ================= Kernel 1: LN1 + QKV GEMM (stage(0) hoisted before LN) =================
__global__ __launch_bounds__(256, 2) void k_ln_qkv(
    const float* __restrict__ x, const float* __restrict__ g, const float* __restrict__ bb,
    const unsigned short* __restrict__ wqkvb, unsigned short* __restrict__ qkv)
{
  __shared__ unsigned short xs[128 * 128];
  __shared__ unsigned short ws[128 * 128];
  __shared__ float redS[128][2], redQ[128][2];
  const int tid = threadIdx.x;
  const long m0 = (long)blockIdx.x * 128;

  stageS128(wqkvb, 128, ws, tid);                // q-chunk weights in flight under LN

  { // LN: 2 threads/row
    const int m = tid >> 1, hf = tid & 1;
    const float4* xg = (const float4*)(x + (size_t)(m0 + m) * 128 + hf * 64);
    float4 xv[16];
    #pragma unroll
    for (int i = 0; i < 16; i++) xv[i] = xg[i];
    float s1 = 0.f, s2 = 0.f;
    #pragma unroll
    for (int i = 0; i < 16; i++) {
      s1 += xv[i].x + xv[i].y + xv[i].z + xv[i].w;
      s2 += xv[i].x * xv[i].x + xv[i].y * xv[i].y + xv[i].z * xv[i].z + xv[i].w * xv[i].w;
    }
    redS[m][hf] = s1; redQ[m][hf] = s2;
    __syncthreads();
    const float mean = (redS[m][0] + redS[m][1]) * (1.f / 128.f);
    const float var  = (redQ[m][0] + redQ[m][1]) * (1.f / 128.f) - mean * mean;
    const float rs = rsqrtf(var + 1e-5f);
    const float4* g4 = (const float4*)(g + hf * 64);
    const float4* b4 = (const float4*)(bb + hf * 64);
    #pragma unroll
    for (int i = 0; i < 8; i++) {
      float4 v0 = xv[2 * i], v1 = xv[2 * i + 1];
      float4 g0 = g4[2 * i], g1 = g4[2 * i + 1], p0 = b4[2 * i], p1 = b4[2 * i + 1];
      uint4 u;
      u.x = pk((v0.x - mean) * rs * g0.x + p0.x, (v0.y - mean) * rs * g0.y + p0.y);
      u.y = pk((v0.z - mean) * rs * g0.z + p0.z, (v0.w - mean) * rs * g0.w + p0.w);
      u.z = pk((v1.x - mean) * rs * g1.x + p1.x, (v1.y - mean) * rs * g1.y + p1.y);
      u.w = pk((v1.z - mean) * rs * g1.z + p1.z, (v1.w - mean) * rs * g1.w + p1.w);
      const int c = hf * 8 + i;
      *(uint4*)&xs[m * 128 + ((c ^ (m & 7)) << 3)] = u;
    }
  }
  const int lane = tid & 63, q = lane >> 4, r = lane & 15;
  const int wv = tid >> 6, wm = wv & 1, wn = wv >> 1;
  for (int nc = 0; nc < 3; nc++) {
    __syncthreads();                             // nc=0: xs+ws ready; nc>0: Cs readout done
    if (nc > 0) {
      stageS128(wqkvb + (size_t)nc * 16384, 128, ws, tid);
      __syncthreads();                           // ws ready
    }
    f32x4 acc[4][4];
    #pragma unroll
    for (int a = 0; a < 4; a++)
      #pragma unroll
      for (int b = 0; b < 4; b++) acc[a][b] = f32x4{0.f, 0.f, 0.f, 0.f};
    gemmS(xs, ws, acc, wm, wn, q, r);
    __syncthreads();                             // ws reads done (reused as Cs)
    storeC(acc, ws, qkv + (size_t)nc * PLANE + (size_t)m0 * 128, 128, tid);
  }
}

// ================= Kernel 2: CSWin attention + fused LePE (in-place into q-plane) ==========
__global__ __launch_bounds__(256, 2) void k_attn(
    const unsigned short* __restrict__ qkv,
    const float* __restrict__ conv_w0, const float* __restrict__ conv_b0,
    const float* __restrict__ conv_w1, const float* __restrict__ conv_b1,
    unsigned short* __restrict__ att)
{
  __shared__ unsigned short Kt[256][40];
  __shared__ unsigned short Vt[32][264];
  __shared__ unsigned short Ps[4][64][72];
  const unsigned short* kpl = qkv + PLANE;
  const unsigned short* vpl = qkv + 2 * PLANE;
  const int t = threadIdx.x;
  const int win = blockIdx.x, head = blockIdx.y, br = blockIdx.z;
  const int bimg = win >> 6, widx = win & 63;
  const int c0 = br * 64 + head * 32;
  const int lgWs = (br == 0) ? 1 : 7;
  const int Wsm1 = (1 << lgWs) - 1;
  const long base = (long)bimg * LDIM + ((br == 0) ? widx * 2 : widx * 256);

  { // stage K + V^T (thread t = key t)
    const long tj = base + (long)(t >> lgWs) * 128 + (t & Wsm1);
    const uint4* kp = (const uint4*)(kpl + (size_t)tj * 128 + c0);
    uint4 k0v = kp[0], k1v = kp[1], k2v = kp[2], k3v = kp[3];
    *(uint4*)&Kt[t][0]  = k0v;  *(uint4*)&Kt[t][8]  = k1v;
    *(uint4*)&Kt[t][16] = k2v;  *(uint4*)&Kt[t][24] = k3v;
    const uint4* vp = (const uint4*)(vpl + (size_t)tj * 128 + c0);
    uint4 vv[4] = {vp[0], vp[1], vp[2], vp[3]};
    const unsigned short* vs = (const unsigned short*)vv;
    #pragma unroll
    for (int d = 0; d < 32; d++) Vt[d][t] = vs[d];
  }
  const int wave = t >> 6, lane = t & 63, q = lane >> 4, r = lane & 15;
  const int qbase = wave * 64;
  bf16x8 qf[4];
  #pragma unroll
  for (int mt = 0; mt < 4; mt++) {
    const int row = qbase + mt * 16 + r;
    const long tok = base + (long)(row >> lgWs) * 128 + (row & Wsm1);
    qf[mt] = *(const bf16x8*)(qkv + (size_t)tok * 128 + c0 + q * 8);
  }
  __syncthreads();

  const float factor = 0.17677669529663687f * 1.44269504088896341f;
  f32x4 Oacc[4][2];
  float psum[4][4];
  #pragma unroll
  for (int mt = 0; mt < 4; mt++) {
    Oacc[mt][0] = f32x4{0.f, 0.f, 0.f, 0.f};
    Oacc[mt][1] = f32x4{0.f, 0.f, 0.f, 0.f};
    #pragma unroll
    for (int rg = 0; rg < 4; rg++) psum[mt][rg] = 0.f;
  }

  for (int kc = 0; kc < 4; kc++) {
    bf16x8 kb[4];
    #pragma unroll
    for (int nt = 0; nt < 4; nt++) kb[nt] = *(const bf16x8*)&Kt[kc * 64 + nt * 16 + r][q * 8];
    f32x4 s[4][4];
    #pragma unroll
    for (int mt = 0; mt < 4; mt++)
      #pragma unroll
      for (int nt = 0; nt < 4; nt++) {
        f32x4 z = f32x4{0.f, 0.f, 0.f, 0.f};
        s[mt][nt] = __builtin_amdgcn_mfma_f32_16x16x32_bf16(qf[mt], kb[nt], z, 0, 0, 0);
      }
    #pragma unroll
    for (int mt = 0; mt < 4; mt++)
      #pragma unroll
      for (int nt = 0; nt < 4; nt++)
        #pragma unroll
        for (int rg = 0; rg < 4; rg++) {
          const float p = __builtin_amdgcn_exp2f(s[mt][nt][rg] * factor);   // max-free
          psum[mt][rg] += p;
          Ps[wave][mt * 16 + q * 4 + rg][nt * 16 + r] = f2bf(p);
        }
    #pragma unroll
    for (int kst = 0; kst < 2; kst++) {
      bf16x8 pa[4], vb[2];
      #pragma unroll
      for (int mt = 0; mt < 4; mt++) pa[mt] = *(const bf16x8*)&Ps[wave][mt * 16 + r][kst * 32 + q * 8];
      #pragma unroll
      for (int nto = 0; nto < 2; nto++) vb[nto] = *(const bf16x8*)&Vt[nto * 16 + r][kc * 64 + kst * 32 + q * 8];
      #pragma unroll
      for (int mt = 0; mt < 4; mt++)
        #pragma unroll
        for (int nto = 0; nto < 2; nto++)
          Oacc[mt][nto] = __builtin_amdgcn_mfma_f32_16x16x32_bf16(pa[mt], vb[nto], Oacc[mt][nto], 0, 0, 0);
    }
  }

  #pragma unroll
  for (int mt = 0; mt < 4; mt++)
    #pragma unroll
    for (int rg = 0; rg < 4; rg++) {
      float v = psum[mt][rg];
      v += __shfl_xor(v, 1); v += __shfl_xor(v, 2);
      v += __shfl_xor(v, 4); v += __shfl_xor(v, 8);
      psum[mt][rg] = __builtin_amdgcn_rcpf(v);
    }

  // ---- fused LePE: depthwise 3x3 over the window, V already staged in Vt ----
  const float* cw = br ? conv_w1 : conv_w0;
  const float* cb = br ? conv_b1 : conv_b0;
  float wle[2][9], ble[2];
  #pragma unroll
  for (int nto = 0; nto < 2; nto++) {
    const int ch = head * 32 + nto * 16 + r;      // channel within branch (0..63)
    ble[nto] = cb[ch];
    #pragma unroll
    for (int tp = 0; tp < 9; tp++) wle[nto][tp] = cw[ch * 9 + tp];
  }
  const int WsW = 1 << lgWs;          // 2 (br0) or 128 (br1)
  const int HsW = 256 >> lgWs;        // 128 (br0) or 2 (br1)

  #pragma unroll
  for (int mt = 0; mt < 4; mt++)
    #pragma unroll
    for (int rg = 0; rg < 4; rg++) {
      const int row = qbase + mt * 16 + q * 4 + rg;      // window token 0..255
      const int ii = row >> lgWs, jj = row & Wsm1;
      const long tok = base + (long)ii * 128 + jj;
      float lep0 = ble[0], lep1 = ble[1];
      #pragma unroll
      for (int di = -1; di <= 1; di++) {
        if ((unsigned)(ii + di) >= (unsigned)HsW) continue;
        #pragma unroll
        for (int dj = -1; dj <= 1; dj++) {
          if ((unsigned)(jj + dj) >= (unsigned)WsW) continue;
          const int nb = row + di * WsW + dj;            // neighbor window token
          const int tap = (di + 1) * 3 + (dj + 1);
          lep0 = fmaf(bflo(Vt[r][nb]),      wle[0][tap], lep0);
          lep1 = fmaf(bflo(Vt[16 + r][nb]), wle[1][tap], lep1);
        }
      }
      const float pr = psum[mt][rg];
      att[(size_t)tok * 128 + c0 + r]      = f2bf(Oacc[mt][0][rg] * pr + lep0);
      att[(size_t)tok * 128 + c0 + 16 + r] = f2bf(Oacc[mt][1][rg] * pr + lep1);
    }
}

// ========== Kernel 3: fused proj + residual + LN2 + FFN1 + GELU + FFN2 + residual ==========
// 256 threads / 4 waves, wave wv owns cols [wv*32,+32) (proven WRITE=65MB regime).
// Weights global->REGISTER with one-phase-ahead prefetch (no ws LDS, no weight vmcnt stalls).
// xs padded +32KB so LDS stays ~66KB -> exactly 2 blocks/CU (avoids round-5 L2 thrash).
__global__ __launch_bounds__(256, 2) void k_projmlp(
    const unsigned short* __restrict__ att, const unsigned short* __restrict__ wprojb,
    const float* __restrict__ b_proj, const float* __restrict__ x,
    const float* __restrict__ g, const float* __restrict__ bb,
    const unsigned short* __restrict__ w1b, const unsigned short* __restrict__ w2b,
    const float* __restrict__ b1, const float* __restrict__ b2,
    float* __restrict__ out)
{
  __shared__ unsigned short hs[64 * 128];            // att tile (proj A), later gelu(h)
  __shared__ unsigned short xs[64 * 128 + 16384];    // LN2 output + 32KB pad (occupancy pin)
  __shared__ float redS[64][4], redQ[64][4];
  const int tid = threadIdx.x;
  const long m0 = (long)blockIdx.x * 64;
  const int lane = tid & 63, q = lane >> 4, r = lane & 15, wv = tid >> 6;

  stageS64(att + (size_t)m0 * 128, hs, tid);

  // wproj B-frags straight to registers (land under the xv loads + barrier)
  bf16x8 wcur[8];
  #pragma unroll
  for (int kc = 0; kc < 4; kc++)
    #pragma unroll
    for (int nt = 0; nt < 2; nt++)
      wcur[kc * 2 + nt] = ldw(wprojb + (size_t)(wv * 32 + nt * 16 + r) * 128 + kc * 32 + q * 8);

  // hoisted residual/param loads
  float xv[4][2][4];
  #pragma unroll
  for (int mt = 0; mt < 4; mt++)
    #pragma unroll
    for (int nt = 0; nt < 2; nt++) {
      const int col = wv * 32 + nt * 16 + r;
      #pragma unroll
      for (int rg = 0; rg < 4; rg++)
        xv[mt][nt][rg] = x[(size_t)(m0 + mt * 16 + q * 4 + rg) * 128 + col];
    }
  float bpv[2], gv[2], bv2[2], b1v[4][2], b2v[2];
  #pragma unroll
  for (int nt = 0; nt < 2; nt++) {
    const int col = wv * 32 + nt * 16 + r;
    bpv[nt] = b_proj[col]; gv[nt] = g[col]; bv2[nt] = bb[col]; b2v[nt] = b2[col];
    #pragma unroll
    for (int nc = 0; nc < 4; nc++) b1v[nc][nt] = b1[nc * 128 + col];
  }
  __syncthreads();                                 // full drain: hs landed, all waves

  // ---- proj GEMM: rows mt*16+q*4+rg (0..63), cols wv*32+nt*16+r; B in registers
  f32x4 xres[4][2];
  #pragma unroll
  for (int mt = 0; mt < 4; mt++) { xres[mt][0] = f32x4{0.f,0.f,0.f,0.f}; xres[mt][1] = f32x4{0.f,0.f,0.f,0.f}; }
  #pragma unroll
  for (int kc = 0; kc < 4; kc++) {
    bf16x8 a[4];
    #pragma unroll
    for (int mt = 0; mt < 4; mt++) a[mt] = fragS(hs, mt * 16 + r, kc * 4 + q);
    #pragma unroll
    for (int mt = 0; mt < 4; mt++)
      #pragma unroll
      for (int nt = 0; nt < 2; nt++)
        xres[mt][nt] = __builtin_amdgcn_mfma_f32_16x16x32_bf16(a[mt], wcur[kc * 2 + nt], xres[mt][nt], 0, 0, 0);
  }
  // prefetch w1[0] frags (covered by residual + LN2 + barriers)
  bf16x8 wnxt[8];
  #pragma unroll
  for (int kc = 0; kc < 4; kc++)
    #pragma unroll
    for (int nt = 0; nt < 2; nt++)
      wnxt[kc * 2 + nt] = ldw(w1b + (size_t)(wv * 32 + nt * 16 + r) * 128 + kc * 32 + q * 8);

  // residual add
  #pragma unroll
  for (int mt = 0; mt < 4; mt++)
    #pragma unroll
    for (int nt = 0; nt < 2; nt++)
      #pragma unroll
      for (int rg = 0; rg < 4; rg++)
        xres[mt][nt][rg] += xv[mt][nt][rg] + bpv[nt];

  // ---- LN2 stats: per-row sums (shfl over r, cross-wave via LDS)
  #pragma unroll
  for (int mt = 0; mt < 4; mt++)
    #pragma unroll
    for (int rg = 0; rg < 4; rg++) {
      float s1 = xres[mt][0][rg] + xres[mt][1][rg];
      float s2 = xres[mt][0][rg] * xres[mt][0][rg] + xres[mt][1][rg] * xres[mt][1][rg];
      s1 += __shfl_xor(s1, 1); s1 += __shfl_xor(s1, 2); s1 += __shfl_xor(s1, 4); s1 += __shfl_xor(s1, 8);
      s2 += __shfl_xor(s2, 1); s2 += __shfl_xor(s2, 2); s2 += __shfl_xor(s2, 4); s2 += __shfl_xor(s2, 8);
      if (r == 0) { const int row = mt * 16 + q * 4 + rg; redS[row][wv] = s1; redQ[row][wv] = s2; }
    }
  barrier_lgkm();                                  // red ready (w1[0] loads stay in flight)
  #pragma unroll
  for (int mt = 0; mt < 4; mt++)
    #pragma unroll
    for (int rg = 0; rg < 4; rg++) {
      const int row = mt * 16 + q * 4 + rg;
      const float s1 = redS[row][0] + redS[row][1] + redS[row][2] + redS[row][3];
      const float s2 = redQ[row][0] + redQ[row][1] + redQ[row][2] + redQ[row][3];
      const float mean = s1 * (1.f / 128.f);
      const float var  = s2 * (1.f / 128.f) - mean * mean;
      const float rs = rsqrtf(var + 1e-5f);
      #pragma unroll
      for (int nt = 0; nt < 2; nt++) {
        const int col = wv * 32 + nt * 16 + r;
        const float v = (xres[mt][nt][rg] - mean) * rs * gv[nt] + bv2[nt];
        xs[row * 128 + ((((col >> 3) ^ (row & 7)) << 3) | (col & 7))] = f2bf(v);
      }
    }
  barrier_lgkm();                                  // xs ready

  // ---- MLP: 4 Dff chunks of 128; register-prefetched weights
  f32x4 oacc[4][2];
  #pragma unroll
  for (int mt = 0; mt < 4; mt++) { oacc[mt][0] = f32x4{0.f,0.f,0.f,0.f}; oacc[mt][1] = f32x4{0.f,0.f,0.f,0.f}; }

  for (int nc = 0; nc < 4; nc++) {
    // wcur <- w1[nc] (prefetched a full phase ago)
    #pragma unroll
    for (int i = 0; i < 8; i++) wcur[i] = wnxt[i];
    // prefetch w2[nc] (covered by GEMM1 + gelu)
    #pragma unroll
    for (int kc = 0; kc < 4; kc++)
      #pragma unroll
      for (int nt = 0; nt < 2; nt++)
        wnxt[kc * 2 + nt] = ldw(w2b + (size_t)(wv * 32 + nt * 16 + r) * 512 + nc * 128 + kc * 32 + q * 8);
    // GEMM1: A from xs, B in registers
    f32x4 h[4][2];
    #pragma unroll
    for (int mt = 0; mt < 4; mt++) { h[mt][0] = f32x4{0.f,0.f,0.f,0.f}; h[mt][1] = f32x4{0.f,0.f,0.f,0.f}; }
    #pragma unroll
    for (int kc = 0; kc < 4; kc++) {
      bf16x8 a[4];
      #pragma unroll
      for (int mt = 0; mt < 4; mt++) a[mt] = fragS(xs, mt * 16 + r, kc * 4 + q);
      #pragma unroll
      for (int mt = 0; mt < 4; mt++)
        #pragma unroll
        for (int nt = 0; nt < 2; nt++)
          h[mt][nt] = __builtin_amdgcn_mfma_f32_16x16x32_bf16(a[mt], wcur[kc * 2 + nt], h[mt][nt], 0, 0, 0);
    }
    barrier_lgkm();                                // prior hs reads done everywhere
    // gelu -> hs (this wave's 32-col strip)
    #pragma unroll
    for (int mt = 0; mt < 4; mt++)
      #pragma unroll
      for (int nt = 0; nt < 2; nt++) {
        const int col = wv * 32 + nt * 16 + r;
        const float bv = b1v[nc][nt];
        #pragma unroll
        for (int rg = 0; rg < 4; rg++) {
          const int rw = mt * 16 + q * 4 + rg;
          hs[rw * 128 + ((((col >> 3) ^ (rw & 7)) << 3) | (col & 7))] = f2bf(gelu_t(h[mt][nt][rg] + bv));
        }
      }
    barrier_lgkm();                                // hs = gelu(h) ready
    // wcur <- w2[nc]; prefetch w1[nc+1] (covered by GEMM2 + next GEMM1)
    #pragma unroll
    for (int i = 0; i < 8; i++) wcur[i] = wnxt[i];
    if (nc < 3) {
      #pragma unroll
      for (int kc = 0; kc < 4; kc++)
        #pragma unroll
        for (int nt = 0; nt < 2; nt++)
          wnxt[kc * 2 + nt] = ldw(w1b + (size_t)((nc + 1) * 128 + wv * 32 + nt * 16 + r) * 128 + kc * 32 + q * 8);
    }
    // GEMM2: A from hs, B in registers
    #pragma unroll
    for (int kc = 0; kc < 4; kc++) {
      bf16x8 a[4];
      #pragma unroll
      for (int mt = 0; mt < 4; mt++) a[mt] = fragS(hs, mt * 16 + r, kc * 4 + q);
      #pragma unroll
      for (int mt = 0; mt < 4; mt++)
        #pragma unroll
        for (int nt = 0; nt < 2; nt++)
          oacc[mt][nt] = __builtin_amdgcn_mfma_f32_16x16x32_bf16(a[mt], wcur[kc * 2 + nt], oacc[mt][nt], 0, 0, 0);
    }
  }
  // ---- epilogue: out = xres + b2 + mlp  (single write, no out-read)
  #pragma unroll
  for (int mt = 0; mt < 4; mt++)
    #pragma unroll
    for (int nt = 0; nt < 2; nt++) {
      const float bv = b2v[nt];
      const int col = wv * 32 + nt * 16 + r;
      #pragma unroll
      for (int rg = 0; rg < 4; rg++) {
        const size_t idx = (size_t)(m0 + mt * 16 + q * 4 + rg) * 128 + col;
        out[idx] = xres[mt][nt][rg] + bv + oacc[mt][nt][rg];
      }
    }
}

extern "C" void kernel_launch(void* const* d_in, const int* in_sizes, int n_in,
                              void* d_out, int out_size, void* d_ws, size_t ws_size,
                              hipStream_t stream) {
  const float* x       = (const float*)d_in[0];
  const float* ln1_g   = (const float*)d_in[1];
  const float* ln1_b   = (const float*)d_in[2];
  const float* w_qkv   = (const float*)d_in[3];
  const float* w_proj  = (const float*)d_in[4];
  const float* b_proj  = (const float*)d_in[5];
  const float* conv_w0 = (const float*)d_in[6];
  const float* conv_b0 = (const float*)d_in[7];
  const float* conv_w1 = (const float*)d_in[8];
  const float* conv_b1 = (const float*)d_in[9];
  const float* ln2_g   = (const float*)d_in[10];
  const float* ln2_b   = (const float*)d_in[11];
  const float* w1      = (const float*)d_in[12];
  const float* b1      = (const float*)d_in[13];
  const float* w2      = (const float*)d_in[14];
  const float* b2      = (const float*)d_in[15];
  float* out = (float*)d_out;

  unsigned short* qkv = (unsigned short*)d_ws;     // 3 planes [NTOK][128]
  unsigned short* att = qkv;                       // attention(+LePE) output in-place in q-plane
  unsigned short* wb  = qkv + 3 * PLANE;           // bf16 weights
  unsigned short* wqkvb  = wb;
  unsigned short* wprojb = wb + 49152;
  unsigned short* w1b    = wb + 65536;
  unsigned short* w2b    = wb + 131072;

  k_prep<<<dim3(192), 256, 0, stream>>>(w_qkv, w_proj, w1, w2, wb);
  k_ln_qkv<<<dim3(NTOK / 128), 256, 0, stream>>>(x, ln1_g, ln1_b, wqkvb, qkv);
  k_attn<<<dim3(512, 2, 2), 256, 0, stream>>>(qkv, conv_w0, conv_b0, conv_w1, conv_b1, att);
  k_projmlp<<<dim3(NTOK / 64), 256, 0, stream>>>(att, wprojb, b_proj, x, ln2_g, ln2_b,
                                                 w1b, w2b, b1, b2, out);
}

// Round 9
// 325.701 us; speedup vs baseline: 1.2037x; 1.0685x over previous
//
#include <hip/hip_runtime.h>
#include <cstddef>

// CSWinBlock on MI355X — round 12: k_attn rebuilt with swapped QK^T (mfma(K,Q)) so P stays
// in registers: cvt_pk packing + bpermute redistribution to the PV A-frag layout. Deletes
// the 36.9KB Ps buffer (LDS 73.7->36.5KB -> 3-4 blocks/CU) + 256 scalar ds_writes + ~1000
// VALU cyc/wave. k_projmlp/k_ln_qkv = round-8 forms (WRITE=65MB verified regime, frozen).
// ws layout (<= 97 MB used):
//   [0, 32MB)    q-plane  bf16 [NTOK][128]  — attention(+LePE) output written IN-PLACE here
//   [32, 64MB)   k-plane  bf16 [NTOK][128]
//   [64, 96MB)   v-plane  bf16 [NTOK][128]
//   [96MB, +384KB) bf16 weights: wqkv[49152] wproj[16384] w1[65536] w2[65536]

#define LDIM 16384
#define NTOK 131072
#define PLANE ((size_t)NTOK * 128)

typedef __attribute__((ext_vector_type(8))) short bf16x8;
typedef __attribute__((ext_vector_type(4))) float f32x4;

__device__ __forceinline__ unsigned short f2bf(float f) {
  union { float f; unsigned int i; } u; u.f = f;
  unsigned int r = u.i + 0x7fffu + ((u.i >> 16) & 1u);
  return (unsigned short)(r >> 16);
}
__device__ __forceinline__ float bflo(unsigned int u) {
  union { unsigned int i; float f; } x; x.i = u << 16; return x.f;
}
__device__ __forceinline__ unsigned int pk(float a, float b) {
  return (unsigned)f2bf(a) | ((unsigned)f2bf(b) << 16);
}
// single-instruction packed f32->bf16 pair (low = a, high = b)
__device__ __forceinline__ unsigned int cvtpk(float a, float b) {
  unsigned int r;
  asm("v_cvt_pk_bf16_f32 %0, %1, %2" : "=v"(r) : "v"(a), "v"(b));
  return r;
}

// async 16B global->LDS (wave-uniform LDS base + lane*16)
__device__ __forceinline__ void async16(const unsigned short* g, unsigned short* l) {
  __builtin_amdgcn_global_load_lds(
      (const __attribute__((address_space(1))) unsigned int*)g,
      (__attribute__((address_space(3))) unsigned int*)l, 16, 0, 0);
}

// barrier that does NOT drain vmcnt: LDS producer/consumer only
__device__ __forceinline__ void barrier_lgkm() {
  asm volatile("s_waitcnt lgkmcnt(0)" ::: "memory");
  __builtin_amdgcn_s_barrier();
  __builtin_amdgcn_sched_barrier(0);
}

// swizzled tile: element (row, col) lives at row*128 + ((col/8)^(row&7))*8 + col%8
__device__ __forceinline__ bf16x8 fragS(const unsigned short* base, int row, int c) {
  return *(const bf16x8*)(base + row * 128 + ((c ^ (row & 7)) << 3));
}

// direct global bf16x8 (one global_load_dwordx4)
__device__ __forceinline__ bf16x8 ldw(const unsigned short* p) {
  return *(const bf16x8*)p;
}

// stage 128x128 bf16 tile global->LDS, swizzled (block-cooperative, 256 threads)
__device__ __forceinline__ void stageS128(const unsigned short* __restrict__ src, int rowStride,
                                          unsigned short* dst, int tid) {
  const int lane = tid & 63, wv = tid >> 6;
  #pragma unroll
  for (int i = 0; i < 8; i++) {
    const int base = i * 256 + wv * 64;     // wave-uniform chunk base
    const int f = base + lane;
    const int row = f >> 4, cs = f & 15, cg = cs ^ (row & 7);
    async16(src + (size_t)row * rowStride + (cg << 3), dst + (size_t)base * 8);
  }
}

// stage 64x128 bf16 tile global->LDS, swizzled (block-cooperative, 256 threads)
__device__ __forceinline__ void stageS64(const unsigned short* __restrict__ src,
                                         unsigned short* dst, int tid) {
  const int lane = tid & 63, wv = tid >> 6;
  #pragma unroll
  for (int i = 0; i < 4; i++) {
    const int base = i * 256 + wv * 64;
    const int f = base + lane;
    const int row = f >> 4, cs = f & 15, cg = cs ^ (row & 7);
    async16(src + (size_t)row * 128 + (cg << 3), dst + (size_t)base * 8);
  }
}

// 128x128x128 MFMA tile, 4 waves in 2x2 (k_ln_qkv)
__device__ __forceinline__ void gemmS(const unsigned short* As, const unsigned short* Bs,
                                      f32x4 acc[4][4], int wm, int wn, int q, int r) {
  #pragma unroll
  for (int kc = 0; kc < 4; kc++) {
    bf16x8 a[4], b[4];
    #pragma unroll
    for (int mt = 0; mt < 4; mt++) a[mt] = fragS(As, wm * 64 + mt * 16 + r, kc * 4 + q);
    #pragma unroll
    for (int nt = 0; nt < 4; nt++) b[nt] = fragS(Bs, wn * 64 + nt * 16 + r, kc * 4 + q);
    #pragma unroll
    for (int mt = 0; mt < 4; mt++)
      #pragma unroll
      for (int nt = 0; nt < 4; nt++)
        acc[mt][nt] = __builtin_amdgcn_mfma_f32_16x16x32_bf16(a[mt], b[nt], acc[mt][nt], 0, 0, 0);
  }
}

// C frags -> swizzled LDS (reuses B tile) -> coalesced bf16 global store (k_ln_qkv)
__device__ __forceinline__ void storeC(f32x4 acc[4][4], unsigned short* Cs,
                                       unsigned short* __restrict__ dst, int dstStride, int tid) {
  const int wv = tid >> 6, lane = tid & 63, q = lane >> 4, r = lane & 15;
  const int wm = wv & 1, wn = wv >> 1;
  #pragma unroll
  for (int mt = 0; mt < 4; mt++)
    #pragma unroll
    for (int nt = 0; nt < 4; nt++) {
      const int col = wn * 64 + nt * 16 + r;
      #pragma unroll
      for (int rg = 0; rg < 4; rg++) {
        const int row = wm * 64 + mt * 16 + q * 4 + rg;
        Cs[row * 128 + ((((col >> 3) ^ (row & 7)) << 3) | (col & 7))] = f2bf(acc[mt][nt][rg]);
      }
    }
  __syncthreads();
  #pragma unroll
  for (int i = 0; i < 8; i++) {
    const int f = tid + i * 256;
    const int row = f >> 4, cs = f & 15, cg = cs ^ (row & 7);
    *(uint4*)(dst + (size_t)row * dstStride + (cg << 3)) = *(const uint4*)(Cs + row * 128 + cs * 8);
  }
}

// gelu tanh-approx: x*sigmoid(1.59576912*(x+0.044715x^3)) = x*rcp(1+exp2(-k*(...)))
__device__ __forceinline__ float gelu_t(float x) {
  const float y = -2.3022083f * (x + 0.044715f * x * x * x);  // -1.59576912*log2(e)*(...)
  const float p = __builtin_amdgcn_exp2f(y);
  return x * __builtin_amdgcn_rcpf(1.f + p);
}

// ================= Kernel 0: weights fp32 -> bf16 =================
__global__ void k_prep(const float* __restrict__ wq, const float* __restrict__ wp,
                       const float* __restrict__ w1, const float* __restrict__ w2,
                       unsigned short* __restrict__ wb)
{
  const int id = blockIdx.x * 256 + threadIdx.x;   // 49152 threads, 4 elems each
  const float* src; int off;
  if (id < 12288)      { src = wq; off = id; }
  else if (id < 16384) { src = wp; off = id - 12288; }
  else if (id < 32768) { src = w1; off = id - 16384; }
  else                 { src = w2; off = id - 32768; }
  const float4 v = *(const float4*)(src + (size_t)off * 4);
  uint2 u; u.x = pk(v.x, v.y); u.y = pk(v.z, v.w);
  *(uint2*)(wb + (size_t)id * 4) = u;
}

// ================= Kernel 1: LN1 + QKV GEMM (stage(0) hoisted before LN) =================
__global__ __launch_bounds__(256, 2) void k_ln_qkv(
    const float* __restrict__ x, const float* __restrict__ g, const float* __restrict__ bb,
    const unsigned short* __restrict__ wqkvb, unsigned short* __restrict__ qkv)
{
  __shared__ unsigned short xs[128 * 128];
  __shared__ unsigned short ws[128 * 128];
  __shared__ float redS[128][2], redQ[128][2];
  const int tid = threadIdx.x;
  const long m0 = (long)blockIdx.x * 128;

  stageS128(wqkvb, 128, ws, tid);                // q-chunk weights in flight under LN

  { // LN: 2 threads/row
    const int m = tid >> 1, hf = tid & 1;
    const float4* xg = (const float4*)(x + (size_t)(m0 + m) * 128 + hf * 64);
    float4 xv[16];
    #pragma unroll
    for (int i = 0; i < 16; i++) xv[i] = xg[i];
    float s1 = 0.f, s2 = 0.f;
    #pragma unroll
    for (int i = 0; i < 16; i++) {
      s1 += xv[i].x + xv[i].y + xv[i].z + xv[i].w;
      s2 += xv[i].x * xv[i].x + xv[i].y * xv[i].y + xv[i].z * xv[i].z + xv[i].w * xv[i].w;
    }
    redS[m][hf] = s1; redQ[m][hf] = s2;
    __syncthreads();
    const float mean = (redS[m][0] + redS[m][1]) * (1.f / 128.f);
    const float var  = (redQ[m][0] + redQ[m][1]) * (1.f / 128.f) - mean * mean;
    const float rs = rsqrtf(var + 1e-5f);
    const float4* g4 = (const float4*)(g + hf * 64);
    const float4* b4 = (const float4*)(bb + hf * 64);
    #pragma unroll
    for (int i = 0; i < 8; i++) {
      float4 v0 = xv[2 * i], v1 = xv[2 * i + 1];
      float4 g0 = g4[2 * i], g1 = g4[2 * i + 1], p0 = b4[2 * i], p1 = b4[2 * i + 1];
      uint4 u;
      u.x = pk((v0.x - mean) * rs * g0.x + p0.x, (v0.y - mean) * rs * g0.y + p0.y);
      u.y = pk((v0.z - mean) * rs * g0.z + p0.z, (v0.w - mean) * rs * g0.w + p0.w);
      u.z = pk((v1.x - mean) * rs * g1.x + p1.x, (v1.y - mean) * rs * g1.y + p1.y);
      u.w = pk((v1.z - mean) * rs * g1.z + p1.z, (v1.w - mean) * rs * g1.w + p1.w);
      const int c = hf * 8 + i;
      *(uint4*)&xs[m * 128 + ((c ^ (m & 7)) << 3)] = u;
    }
  }
  const int lane = tid & 63, q = lane >> 4, r = lane & 15;
  const int wv = tid >> 6, wm = wv & 1, wn = wv >> 1;
  for (int nc = 0; nc < 3; nc++) {
    __syncthreads();                             // nc=0: xs+ws ready; nc>0: Cs readout done
    if (nc > 0) {
      stageS128(wqkvb + (size_t)nc * 16384, 128, ws, tid);
      __syncthreads();                           // ws ready
    }
    f32x4 acc[4][4];
    #pragma unroll
    for (int a = 0; a < 4; a++)
      #pragma unroll
      for (int b = 0; b < 4; b++) acc[a][b] = f32x4{0.f, 0.f, 0.f, 0.f};
    gemmS(xs, ws, acc, wm, wn, q, r);
    __syncthreads();                             // ws reads done (reused as Cs)
    storeC(acc, ws, qkv + (size_t)nc * PLANE + (size_t)m0 * 128, 128, tid);
  }
}

// ================= Kernel 2: CSWin attention + fused LePE, register-resident P ============
// Swapped QK^T: s2 = mfma(K,Q) -> lane (q,r) holds P[k=nt*16+q*4+rg][qtok=mt*16+r].
// P packed to bf16 pairs in-register (cvt_pk) and redistributed to the PV A-frag layout
// via __shfl: target (q,r) pulls words from lanes (q&1)*32+r and +16, register
// nt_s = kst*2+(q>>1) (both halves computed, cndmask on lane&32). No Ps LDS buffer.
__global__ __launch_bounds__(256, 3) void k_attn(
    const unsigned short* __restrict__ qkv,
    const float* __restrict__ conv_w0, const float* __restrict__ conv_b0,
    const float* __restrict__ conv_w1, const float* __restrict__ conv_b1,
    unsigned short* __restrict__ att)
{
  __shared__ unsigned short Kt[256][40];
  __shared__ unsigned short Vt[32][264];
  const unsigned short* kpl = qkv + PLANE;
  const unsigned short* vpl = qkv + 2 * PLANE;
  const int t = threadIdx.x;
  const int win = blockIdx.x, head = blockIdx.y, br = blockIdx.z;
  const int bimg = win >> 6, widx = win & 63;
  const int c0 = br * 64 + head * 32;
  const int lgWs = (br == 0) ? 1 : 7;
  const int Wsm1 = (1 << lgWs) - 1;
  const long base = (long)bimg * LDIM + ((br == 0) ? widx * 2 : widx * 256);

  { // stage K + V^T (thread t = key t)
    const long tj = base + (long)(t >> lgWs) * 128 + (t & Wsm1);
    const uint4* kp = (const uint4*)(kpl + (size_t)tj * 128 + c0);
    uint4 k0v = kp[0], k1v = kp[1], k2v = kp[2], k3v = kp[3];
    *(uint4*)&Kt[t][0]  = k0v;  *(uint4*)&Kt[t][8]  = k1v;
    *(uint4*)&Kt[t][16] = k2v;  *(uint4*)&Kt[t][24] = k3v;
    const uint4* vp = (const uint4*)(vpl + (size_t)tj * 128 + c0);
    uint4 vv[4] = {vp[0], vp[1], vp[2], vp[3]};
    const unsigned short* vs = (const unsigned short*)vv;
    #pragma unroll
    for (int d = 0; d < 32; d++) Vt[d][t] = vs[d];
  }
  const int wave = t >> 6, lane = t & 63, q = lane >> 4, r = lane & 15;
  const int qbase = wave * 64;
  bf16x8 qf[4];
  #pragma unroll
  for (int mt = 0; mt < 4; mt++) {
    const int row = qbase + mt * 16 + r;
    const long tok = base + (long)(row >> lgWs) * 128 + (row & Wsm1);
    qf[mt] = *(const bf16x8*)(qkv + (size_t)tok * 128 + c0 + q * 8);
  }
  __syncthreads();

  const float factor = 0.17677669529663687f * 1.44269504088896341f;
  f32x4 Oacc[4][2];
  float part[4];                       // partial denominators, qtok = mt*16 + r
  #pragma unroll
  for (int mt = 0; mt < 4; mt++) {
    Oacc[mt][0] = f32x4{0.f, 0.f, 0.f, 0.f};
    Oacc[mt][1] = f32x4{0.f, 0.f, 0.f, 0.f};
    part[mt] = 0.f;
  }
  const int la = ((lane >> 4) & 1) * 32 + r;   // source lane A for P redistribution
  const int lb = la + 16;                      // source lane B
  const bool hiq = (lane & 32) != 0;           // q >= 2

  for (int kc = 0; kc < 4; kc++) {
    unsigned int pk32[4][4][2];                // [nt][mt][word]: bf16 pairs of P
    #pragma unroll
    for (int nt = 0; nt < 4; nt++) {
      const bf16x8 kb = *(const bf16x8*)&Kt[kc * 64 + nt * 16 + r][q * 8];
      f32x4 s4[4];
      #pragma unroll
      for (int mt = 0; mt < 4; mt++) {
        f32x4 z = f32x4{0.f, 0.f, 0.f, 0.f};
        s4[mt] = __builtin_amdgcn_mfma_f32_16x16x32_bf16(kb, qf[mt], z, 0, 0, 0);
      }
      #pragma unroll
      for (int mt = 0; mt < 4; mt++) {
        const float p0 = __builtin_amdgcn_exp2f(s4[mt][0] * factor);
        const float p1 = __builtin_amdgcn_exp2f(s4[mt][1] * factor);
        const float p2 = __builtin_amdgcn_exp2f(s4[mt][2] * factor);
        const float p3 = __builtin_amdgcn_exp2f(s4[mt][3] * factor);
        part[mt] += (p0 + p1) + (p2 + p3);
        pk32[nt][mt][0] = cvtpk(p0, p1);
        pk32[nt][mt][1] = cvtpk(p2, p3);
      }
    }
    #pragma unroll
    for (int kst = 0; kst < 2; kst++) {
      bf16x8 vb[2];
      #pragma unroll
      for (int nto = 0; nto < 2; nto++)
        vb[nto] = *(const bf16x8*)&Vt[nto * 16 + r][kc * 64 + kst * 32 + q * 8];
      #pragma unroll
      for (int mt = 0; mt < 4; mt++) {
        const unsigned int a0 = __shfl(pk32[kst * 2][mt][0], la);
        const unsigned int a1 = __shfl(pk32[kst * 2][mt][1], la);
        const unsigned int a2 = __shfl(pk32[kst * 2][mt][0], lb);
        const unsigned int a3 = __shfl(pk32[kst * 2][mt][1], lb);
        const unsigned int b0 = __shfl(pk32[kst * 2 + 1][mt][0], la);
        const unsigned int b1 = __shfl(pk32[kst * 2 + 1][mt][1], la);
        const unsigned int b2 = __shfl(pk32[kst * 2 + 1][mt][0], lb);
        const unsigned int b3 = __shfl(pk32[kst * 2 + 1][mt][1], lb);
        union { uint4 u; bf16x8 v; } cv;
        cv.u.x = hiq ? b0 : a0;
        cv.u.y = hiq ? b1 : a1;
        cv.u.z = hiq ? b2 : a2;
        cv.u.w = hiq ? b3 : a3;
        #pragma unroll
        for (int nto = 0; nto < 2; nto++)
          Oacc[mt][nto] = __builtin_amdgcn_mfma_f32_16x16x32_bf16(cv.v, vb[nto], Oacc[mt][nto], 0, 0, 0);
      }
    }
  }

  // softmax normalization: reduce part across q-groups, redistribute to C-layout, fold in
  #pragma unroll
  for (int mt = 0; mt < 4; mt++) {
    float v = part[mt];
    v += __shfl_xor(v, 16); v += __shfl_xor(v, 32);
    v = __builtin_amdgcn_rcpf(v);
    #pragma unroll
    for (int rg = 0; rg < 4; rg++) {
      const float s = __shfl(v, (lane & 48) + q * 4 + rg);
      Oacc[mt][0][rg] *= s;
      Oacc[mt][1][rg] *= s;
    }
  }

  // ---- fused LePE: depthwise 3x3 over the window, V already staged in Vt ----
  const float* cw = br ? conv_w1 : conv_w0;
  const float* cb = br ? conv_b1 : conv_b0;
  float wle[2][9], ble[2];
  #pragma unroll
  for (int nto = 0; nto < 2; nto++) {
    const int ch = head * 32 + nto * 16 + r;      // channel within branch (0..63)
    ble[nto] = cb[ch];
    #pragma unroll
    for (int tp = 0; tp < 9; tp++) wle[nto][tp] = cw[ch * 9 + tp];
  }
  const int WsW = 1 << lgWs;          // 2 (br0) or 128 (br1)
  const int HsW = 256 >> lgWs;        // 128 (br0) or 2 (br1)

  #pragma unroll
  for (int mt = 0; mt < 4; mt++)
    #pragma unroll
    for (int rg = 0; rg < 4; rg++) {
      const int row = qbase + mt * 16 + q * 4 + rg;      // window token 0..255
      const int ii = row >> lgWs, jj = row & Wsm1;
      const long tok = base + (long)ii * 128 + jj;
      float lep0 = ble[0], lep1 = ble[1];
      #pragma unroll
      for (int di = -1; di <= 1; di++) {
        if ((unsigned)(ii + di) >= (unsigned)HsW) continue;
        #pragma unroll
        for (int dj = -1; dj <= 1; dj++) {
          if ((unsigned)(jj + dj) >= (unsigned)WsW) continue;
          const int nb = row + di * WsW + dj;            // neighbor window token
          const int tap = (di + 1) * 3 + (dj + 1);
          lep0 = fmaf(bflo(Vt[r][nb]),      wle[0][tap], lep0);
          lep1 = fmaf(bflo(Vt[16 + r][nb]), wle[1][tap], lep1);
        }
      }
      att[(size_t)tok * 128 + c0 + r]      = f2bf(Oacc[mt][0][rg] + lep0);
      att[(size_t)tok * 128 + c0 + 16 + r] = f2bf(Oacc[mt][1][rg] + lep1);
    }
}

// ========== Kernel 3: fused proj + residual + LN2 + FFN1 + GELU + FFN2 + residual ==========
// 256 threads / 4 waves, wave wv owns cols [wv*32,+32) (proven WRITE=65MB regime).
// Weights global->REGISTER with one-phase-ahead prefetch. xs padded +32KB -> 2 blocks/CU.
__global__ __launch_bounds__(256, 2) void k_projmlp(
    const unsigned short* __restrict__ att, const unsigned short* __restrict__ wprojb,
    const float* __restrict__ b_proj, const float* __restrict__ x,
    const float* __restrict__ g, const float* __restrict__ bb,
    const unsigned short* __restrict__ w1b, const unsigned short* __restrict__ w2b,
    const float* __restrict__ b1, const float* __restrict__ b2,
    float* __restrict__ out)
{
  __shared__ unsigned short hs[64 * 128];            // att tile (proj A), later gelu(h)
  __shared__ unsigned short xs[64 * 128 + 16384];    // LN2 output + 32KB pad (occupancy pin)
  __shared__ float redS[64][4], redQ[64][4];
  const int tid = threadIdx.x;
  const long m0 = (long)blockIdx.x * 64;
  const int lane = tid & 63, q = lane >> 4, r = lane & 15, wv = tid >> 6;

  stageS64(att + (size_t)m0 * 128, hs, tid);

  // wproj B-frags straight to registers (land under the xv loads + barrier)
  bf16x8 wcur[8];
  #pragma unroll
  for (int kc = 0; kc < 4; kc++)
    #pragma unroll
    for (int nt = 0; nt < 2; nt++)
      wcur[kc * 2 + nt] = ldw(wprojb + (size_t)(wv * 32 + nt * 16 + r) * 128 + kc * 32 + q * 8);

  // hoisted residual/param loads
  float xv[4][2][4];
  #pragma unroll
  for (int mt = 0; mt < 4; mt++)
    #pragma unroll
    for (int nt = 0; nt < 2; nt++) {
      const int col = wv * 32 + nt * 16 + r;
      #pragma unroll
      for (int rg = 0; rg < 4; rg++)
        xv[mt][nt][rg] = x[(size_t)(m0 + mt * 16 + q * 4 + rg) * 128 + col];
    }
  float bpv[2], gv[2], bv2[2], b1v[4][2], b2v[2];
  #pragma unroll
  for (int nt = 0; nt < 2; nt++) {
    const int col = wv * 32 + nt * 16 + r;
    bpv[nt] = b_proj[col]; gv[nt] = g[col]; bv2[nt] = bb[col]; b2v[nt] = b2[col];
    #pragma unroll
    for (int nc = 0; nc < 4; nc++) b1v[nc][nt] = b1[nc * 128 + col];
  }
  __syncthreads();                                 // full drain: hs landed, all waves

  // ---- proj GEMM: rows mt*16+q*4+rg (0..63), cols wv*32+nt*16+r; B in registers
  f32x4 xres[4][2];
  #pragma unroll
  for (int mt = 0; mt < 4; mt++) { xres[mt][0] = f32x4{0.f,0.f,0.f,0.f}; xres[mt][1] = f32x4{0.f,0.f,0.f,0.f}; }
  #pragma unroll
  for (int kc = 0; kc < 4; kc++) {
    bf16x8 a[4];
    #pragma unroll
    for (int mt = 0; mt < 4; mt++) a[mt] = fragS(hs, mt * 16 + r, kc * 4 + q);
    #pragma unroll
    for (int mt = 0; mt < 4; mt++)
      #pragma unroll
      for (int nt = 0; nt < 2; nt++)
        xres[mt][nt] = __builtin_amdgcn_mfma_f32_16x16x32_bf16(a[mt], wcur[kc * 2 + nt], xres[mt][nt], 0, 0, 0);
  }
  // prefetch w1[0] frags (covered by residual + LN2 + barriers)
  bf16x8 wnxt[8];
  #pragma unroll
  for (int kc = 0; kc < 4; kc++)
    #pragma unroll
    for (int nt = 0; nt < 2; nt++)
      wnxt[kc * 2 + nt] = ldw(w1b + (size_t)(wv * 32 + nt * 16 + r) * 128 + kc * 32 + q * 8);

  // residual add
  #pragma unroll
  for (int mt = 0; mt < 4; mt++)
    #pragma unroll
    for (int nt = 0; nt < 2; nt++)
      #pragma unroll
      for (int rg = 0; rg < 4; rg++)
        xres[mt][nt][rg] += xv[mt][nt][rg] + bpv[nt];

  // ---- LN2 stats: per-row sums (shfl over r, cross-wave via LDS)
  #pragma unroll
  for (int mt = 0; mt < 4; mt++)
    #pragma unroll
    for (int rg = 0; rg < 4; rg++) {
      float s1 = xres[mt][0][rg] + xres[mt][1][rg];
      float s2 = xres[mt][0][rg] * xres[mt][0][rg] + xres[mt][1][rg] * xres[mt][1][rg];
      s1 += __shfl_xor(s1, 1); s1 += __shfl_xor(s1, 2); s1 += __shfl_xor(s1, 4); s1 += __shfl_xor(s1, 8);
      s2 += __shfl_xor(s2, 1); s2 += __shfl_xor(s2, 2); s2 += __shfl_xor(s2, 4); s2 += __shfl_xor(s2, 8);
      if (r == 0) { const int row = mt * 16 + q * 4 + rg; redS[row][wv] = s1; redQ[row][wv] = s2; }
    }
  barrier_lgkm();                                  // red ready (w1[0] loads stay in flight)
  #pragma unroll
  for (int mt = 0; mt < 4; mt++)
    #pragma unroll
    for (int rg = 0; rg < 4; rg++) {
      const int row = mt * 16 + q * 4 + rg;
      const float s1 = redS[row][0] + redS[row][1] + redS[row][2] + redS[row][3];
      const float s2 = redQ[row][0] + redQ[row][1] + redQ[row][2] + redQ[row][3];
      const float mean = s1 * (1.f / 128.f);
      const float var  = s2 * (1.f / 128.f) - mean * mean;
      const float rs = rsqrtf(var + 1e-5f);
      #pragma unroll
      for (int nt = 0; nt < 2; nt++) {
        const int col = wv * 32 + nt * 16 + r;
        const float v = (xres[mt][nt][rg] - mean) * rs * gv[nt] + bv2[nt];
        xs[row * 128 + ((((col >> 3) ^ (row & 7)) << 3) | (col & 7))] = f2bf(v);
      }
    }
  barrier_lgkm();                                  // xs ready

  // ---- MLP: 4 Dff chunks of 128; register-prefetched weights
  f32x4 oacc[4][2];
  #pragma unroll
  for (int mt = 0; mt < 4; mt++) { oacc[mt][0] = f32x4{0.f,0.f,0.f,0.f}; oacc[mt][1] = f32x4{0.f,0.f,0.f,0.f}; }

  for (int nc = 0; nc < 4; nc++) {
    // wcur <- w1[nc] (prefetched a full phase ago)
    #pragma unroll
    for (int i = 0; i < 8; i++) wcur[i] = wnxt[i];
    // prefetch w2[nc] (covered by GEMM1 + gelu)
    #pragma unroll
    for (int kc = 0; kc < 4; kc++)
      #pragma unroll
      for (int nt = 0; nt < 2; nt++)
        wnxt[kc * 2 + nt] = ldw(w2b + (size_t)(wv * 32 + nt * 16 + r) * 512 + nc * 128 + kc * 32 + q * 8);
    // GEMM1: A from xs, B in registers
    f32x4 h[4][2];
    #pragma unroll
    for (int mt = 0; mt < 4; mt++) { h[mt][0] = f32x4{0.f,0.f,0.f,0.f}; h[mt][1] = f32x4{0.f,0.f,0.f,0.f}; }
    #pragma unroll
    for (int kc = 0; kc < 4; kc++) {
      bf16x8 a[4];
      #pragma unroll
      for (int mt = 0; mt < 4; mt++) a[mt] = fragS(xs, mt * 16 + r, kc * 4 + q);
      #pragma unroll
      for (int mt = 0; mt < 4; mt++)
        #pragma unroll
        for (int nt = 0; nt < 2; nt++)
          h[mt][nt] = __builtin_amdgcn_mfma_f32_16x16x32_bf16(a[mt], wcur[kc * 2 + nt], h[mt][nt], 0, 0, 0);
    }
    barrier_lgkm();                                // prior hs reads done everywhere
    // gelu -> hs (this wave's 32-col strip)
    #pragma unroll
    for (int mt = 0; mt < 4; mt++)
      #pragma unroll
      for (int nt = 0; nt < 2; nt++) {
        const int col = wv * 32 + nt * 16 + r;
        const float bv = b1v[nc][nt];
        #pragma unroll
        for (int rg = 0; rg < 4; rg++) {
          const int rw = mt * 16 + q * 4 + rg;
          hs[rw * 128 + ((((col >> 3) ^ (rw & 7)) << 3) | (col & 7))] = f2bf(gelu_t(h[mt][nt][rg] + bv));
        }
      }
    barrier_lgkm();                                // hs = gelu(h) ready
    // wcur <- w2[nc]; prefetch w1[nc+1] (covered by GEMM2 + next GEMM1)
    #pragma unroll
    for (int i = 0; i < 8; i++) wcur[i] = wnxt[i];
    if (nc < 3) {
      #pragma unroll
      for (int kc = 0; kc < 4; kc++)
        #pragma unroll
        for (int nt = 0; nt < 2; nt++)
          wnxt[kc * 2 + nt] = ldw(w1b + (size_t)((nc + 1) * 128 + wv * 32 + nt * 16 + r) * 128 + kc * 32 + q * 8);
    }
    // GEMM2: A from hs, B in registers
    #pragma unroll
    for (int kc = 0; kc < 4; kc++) {
      bf16x8 a[4];
      #pragma unroll
      for (int mt = 0; mt < 4; mt++) a[mt] = fragS(hs, mt * 16 + r, kc * 4 + q);
      #pragma unroll
      for (int mt = 0; mt < 4; mt++)
        #pragma unroll
        for (int nt = 0; nt < 2; nt++)
          oacc[mt][nt] = __builtin_amdgcn_mfma_f32_16x16x32_bf16(a[mt], wcur[kc * 2 + nt], oacc[mt][nt], 0, 0, 0);
    }
  }
  // ---- epilogue: out = xres + b2 + mlp  (single write, no out-read)
  #pragma unroll
  for (int mt = 0; mt < 4; mt++)
    #pragma unroll
    for (int nt = 0; nt < 2; nt++) {
      const float bv = b2v[nt];
      const int col = wv * 32 + nt * 16 + r;
      #pragma unroll
      for (int rg = 0; rg < 4; rg++) {
        const size_t idx = (size_t)(m0 + mt * 16 + q * 4 + rg) * 128 + col;
        out[idx] = xres[mt][nt][rg] + bv + oacc[mt][nt][rg];
      }
    }
}

extern "C" void kernel_launch(void* const* d_in, const int* in_sizes, int n_in,
                              void* d_out, int out_size, void* d_ws, size_t ws_size,
                              hipStream_t stream) {
  const float* x       = (const float*)d_in[0];
  const float* ln1_g   = (const float*)d_in[1];
  const float* ln1_b   = (const float*)d_in[2];
  const float* w_qkv   = (const float*)d_in[3];
  const float* w_proj  = (const float*)d_in[4];
  const float* b_proj  = (const float*)d_in[5];
  const float* conv_w0 = (const float*)d_in[6];
  const float* conv_b0 = (const float*)d_in[7];
  const float* conv_w1 = (const float*)d_in[8];
  const float* conv_b1 = (const float*)d_in[9];
  const float* ln2_g   = (const float*)d_in[10];
  const float* ln2_b   = (const float*)d_in[11];
  const float* w1      = (const float*)d_in[12];
  const float* b1      = (const float*)d_in[13];
  const float* w2      = (const float*)d_in[14];
  const float* b2      = (const float*)d_in[15];
  float* out = (float*)d_out;

  unsigned short* qkv = (unsigned short*)d_ws;     // 3 planes [NTOK][128]
  unsigned short* att = qkv;                       // attention(+LePE) output in-place in q-plane
  unsigned short* wb  = qkv + 3 * PLANE;           // bf16 weights
  unsigned short* wqkvb  = wb;
  unsigned short* wprojb = wb + 49152;
  unsigned short* w1b    = wb + 65536;
  unsigned short* w2b    = wb + 131072;

  k_prep<<<dim3(192), 256, 0, stream>>>(w_qkv, w_proj, w1, w2, wb);
  k_ln_qkv<<<dim3(NTOK / 128), 256, 0, stream>>>(x, ln1_g, ln1_b, wqkvb, qkv);
  k_attn<<<dim3(512, 2, 2), 256, 0, stream>>>(qkv, conv_w0, conv_b0, conv_w1, conv_b1, att);
  k_projmlp<<<dim3(NTOK / 64), 256, 0, stream>>>(att, wprojb, b_proj, x, ln2_g, ln2_b,
                                                 w1b, w2b, b1, b2, out);
}